// Round 7
// baseline (541.238 us; speedup 1.0000x reference)
//
#include <hip/hip_runtime.h>

// GCN 2-layer inference: CSR gather w/ bf16 payload, packed (src,w) CSR entries.
// CSR build via 2-level dst-range bucketing: partition pass (sequential writes),
// then per-XCD deg/fill passes whose working sets fit the local 4MB L2.
static constexpr int NPAD = 131072;
typedef unsigned int uint32;

__device__ __forceinline__ ushort f2bf(float f) {  // RNE f32->bf16
  uint32 u = __float_as_uint(f);
  return (ushort)((u + 0x7FFF + ((u >> 16) & 1)) >> 16);
}
__device__ __forceinline__ float bf_lo(uint32 u) { return __uint_as_float(u << 16); }
__device__ __forceinline__ float bf_hi(uint32 u) { return __uint_as_float(u & 0xFFFF0000u); }
__device__ __forceinline__ float bfu(ushort u) { return __uint_as_float((uint32)u << 16); }

// ---- bucket meta: bmeta[0..8] = exclusive bucket bases (bmeta[8]=E),
//                   bmeta[9..16] = running cursors for the partition pass.
__global__ __launch_bounds__(256) void count_buckets_kernel(const int* __restrict__ dst,
                                                            int* __restrict__ bcnt,
                                                            int nE, int nPer) {
  __shared__ int c[8];
  if (threadIdx.x < 8) c[threadIdx.x] = 0;
  __syncthreads();
  for (int i = blockIdx.x * 256 + threadIdx.x; i < nE; i += gridDim.x * 256) {
    int g = dst[i] / nPer;
    atomicAdd(&c[min(g, 7)], 1);
  }
  __syncthreads();
  if (threadIdx.x < 8 && c[threadIdx.x]) atomicAdd(&bcnt[threadIdx.x], c[threadIdx.x]);
}

__global__ __launch_bounds__(64) void bucket_scan_kernel(const int* __restrict__ bcnt,
                                                         int* __restrict__ bmeta) {
  if (threadIdx.x == 0) {
    int acc = 0;
    for (int g = 0; g < 8; ++g) {
      bmeta[g] = acc;
      bmeta[9 + g] = acc;
      acc += bcnt[g];
    }
    bmeta[8] = acc;  // = E
  }
}

// Partition edges into dst-range buckets. Per 256-edge chunk: LDS rank within
// bucket, one cursor atomic per bucket per chunk, coalesced packed writes.
__global__ __launch_bounds__(256) void partition_kernel(const int* __restrict__ src,
                                                        const int* __restrict__ dst,
                                                        int* __restrict__ bmeta,
                                                        uint2* __restrict__ bucket,
                                                        int nE, int nPer) {
  __shared__ int cnt[8];
  __shared__ int base[8];
  const int nChunk = (nE + 255) / 256;
  for (int chunk = blockIdx.x; chunk < nChunk; chunk += gridDim.x) {
    int i = chunk * 256 + threadIdx.x;
    if (threadIdx.x < 8) cnt[threadIdx.x] = 0;
    __syncthreads();
    int g = 0, rank = 0, s = 0, d = 0;
    bool act = (i < nE);
    if (act) {
      d = dst[i]; s = src[i];
      g = min(d / nPer, 7);
      rank = atomicAdd(&cnt[g], 1);
    }
    __syncthreads();
    if (threadIdx.x < 8 && cnt[threadIdx.x] > 0)
      base[threadIdx.x] = atomicAdd(&bmeta[9 + threadIdx.x], cnt[threadIdx.x]);
    __syncthreads();
    if (act) bucket[base[g] + rank] = make_uint2((uint32)s, (uint32)d);
    __syncthreads();
  }
}

// Per-XCD degree histogram over the local bucket (degi slice is L2-resident).
__global__ __launch_bounds__(256) void deg2_kernel(const uint2* __restrict__ bucket,
                                                   const int* __restrict__ bmeta,
                                                   int* __restrict__ degi) {
  const int xcd = blockIdx.x & 7;
  const int sub = blockIdx.x >> 3;
  const int nsub = gridDim.x >> 3;
  const int b0 = bmeta[xcd], b1 = bmeta[xcd + 1];
  for (int i = b0 + sub * 256 + threadIdx.x; i < b1; i += nsub * 256)
    atomicAdd(&degi[bucket[i].y], 1);
}

__global__ __launch_bounds__(256) void dis_kernel(const int* __restrict__ degi,
                                                  float* __restrict__ dis, int n) {
  int i = blockIdx.x * 256 + threadIdx.x;
  if (i < n) dis[i] = rsqrtf((float)degi[i] + 1.0f);  // +1 = self loop
}

__global__ __launch_bounds__(256) void block_sum_kernel(const int* __restrict__ degi,
                                                        int* __restrict__ bsum, int n) {
  __shared__ int sm[256];
  int i = blockIdx.x * 256 + threadIdx.x;
  sm[threadIdx.x] = (i < n) ? degi[i] : 0;
  __syncthreads();
  for (int s = 128; s > 0; s >>= 1) {
    if (threadIdx.x < s) sm[threadIdx.x] += sm[threadIdx.x + s];
    __syncthreads();
  }
  if (threadIdx.x == 0) bsum[blockIdx.x] = sm[0];
}

__global__ __launch_bounds__(512) void scan_bsum_kernel(int* __restrict__ bsum, int nb) {
  __shared__ int sm[512];
  int v = (threadIdx.x < nb) ? bsum[threadIdx.x] : 0;
  sm[threadIdx.x] = v;
  __syncthreads();
  for (int off = 1; off < 512; off <<= 1) {
    int t = (threadIdx.x >= off) ? sm[threadIdx.x - off] : 0;
    __syncthreads();
    sm[threadIdx.x] += t;
    __syncthreads();
  }
  if (threadIdx.x < nb) bsum[threadIdx.x] = sm[threadIdx.x] - v;  // exclusive
}

__global__ __launch_bounds__(256) void scan_local_kernel(const int* __restrict__ degi,
                                                         const int* __restrict__ bsum,
                                                         int* __restrict__ row_start,
                                                         int* __restrict__ cursor, int n) {
  __shared__ int sm[256];
  int i = blockIdx.x * 256 + threadIdx.x;
  int v = (i < n) ? degi[i] : 0;
  sm[threadIdx.x] = v;
  __syncthreads();
  for (int off = 1; off < 256; off <<= 1) {
    int t = (threadIdx.x >= off) ? sm[threadIdx.x - off] : 0;
    __syncthreads();
    sm[threadIdx.x] += t;
    __syncthreads();
  }
  int excl = sm[threadIdx.x] - v + bsum[blockIdx.x];
  if (i < n) { row_start[i] = excl; cursor[i] = excl; }
  if (i == n - 1) row_start[n] = excl + v;  // = E
}

// Per-XCD CSR fill from the local bucket; dirty CSR slice (1.6MB) + cursors
// (50KB) + bucket stream (1.6MB) all fit the local L2.
__global__ __launch_bounds__(256) void fill2_kernel(const uint2* __restrict__ bucket,
                                                    const int* __restrict__ bmeta,
                                                    const float* __restrict__ dis,
                                                    int* __restrict__ cursor,
                                                    uint2* __restrict__ csr_pack) {
  const int xcd = blockIdx.x & 7;
  const int sub = blockIdx.x >> 3;
  const int nsub = gridDim.x >> 3;
  const int b0 = bmeta[xcd], b1 = bmeta[xcd + 1];
  for (int i = b0 + sub * 256 + threadIdx.x; i < b1; i += nsub * 256) {
    uint2 e = bucket[i];
    int pos = atomicAdd(&cursor[e.y], 1);
    csr_pack[pos] = make_uint2(e.x, __float_as_uint(dis[e.x] * dis[e.y]));
  }
}

// H_bf16[128rows x COLS] = (relu?)X[128rows x 128] @ W[128 x COLS]; X fp32 or bf16.
template <int COLS, bool RELU_IN, bool IN_BF16>
__global__ __launch_bounds__(256) void gemm_kernel(const void* __restrict__ Xv,
                                                   const float* __restrict__ W,
                                                   ushort* __restrict__ H, int n) {
  constexpr int KC = 32;
  constexpr int RT = 132;
  constexpr int TN = (COLS == 128) ? 8 : 4;
  __shared__ float sX[KC][RT];
  __shared__ float sW[KC][COLS];
  const int t = threadIdx.x;
  const int row0 = blockIdx.x * 128;
  const int r0 = (t >> 4) * 8;
  const int c0 = (t & 15) * 4;

  float acc[8][TN];
#pragma unroll
  for (int i = 0; i < 8; ++i)
#pragma unroll
    for (int j = 0; j < TN; ++j) acc[i][j] = 0.f;

  for (int k0 = 0; k0 < 128; k0 += KC) {
#pragma unroll
    for (int p = 0; p < 4; ++p) {
      int idx = p * 256 + t;
      int r = idx >> 3;
      int f = idx & 7;
      int gr = row0 + r;
      float4 v = make_float4(0.f, 0.f, 0.f, 0.f);
      if (gr < n) {
        if (IN_BF16) {
          const ushort* Xb = (const ushort*)Xv;
          ushort4 uv = *(const ushort4*)(Xb + (size_t)gr * 128 + k0 + f * 4);
          v = make_float4(bfu(uv.x), bfu(uv.y), bfu(uv.z), bfu(uv.w));
        } else {
          v = *(const float4*)((const float*)Xv + (size_t)gr * 128 + k0 + f * 4);
        }
      }
      if (RELU_IN) {
        v.x = fmaxf(v.x, 0.f); v.y = fmaxf(v.y, 0.f);
        v.z = fmaxf(v.z, 0.f); v.w = fmaxf(v.w, 0.f);
      }
      int kk = f * 4;
      sX[kk + 0][r] = v.x; sX[kk + 1][r] = v.y;
      sX[kk + 2][r] = v.z; sX[kk + 3][r] = v.w;
    }
    constexpr int WP = (KC * COLS) / (256 * 4);
#pragma unroll
    for (int p = 0; p < WP; ++p) {
      int idx = p * 256 + t;
      int k = idx / (COLS / 4);
      int c4 = idx % (COLS / 4);
      *(float4*)&sW[k][c4 * 4] = *(const float4*)(W + (size_t)(k0 + k) * COLS + c4 * 4);
    }
    __syncthreads();
#pragma unroll 8
    for (int k = 0; k < KC; ++k) {
      float4 xa = *(const float4*)&sX[k][r0];
      float4 xb = *(const float4*)&sX[k][r0 + 4];
      float4 wa = *(const float4*)&sW[k][c0];
      float xr[8] = {xa.x, xa.y, xa.z, xa.w, xb.x, xb.y, xb.z, xb.w};
      if (COLS == 128) {
        float4 wb = *(const float4*)&sW[k][c0 + 64];
        float wr[8] = {wa.x, wa.y, wa.z, wa.w, wb.x, wb.y, wb.z, wb.w};
#pragma unroll
        for (int i = 0; i < 8; ++i)
#pragma unroll
          for (int j = 0; j < 8; ++j) acc[i][j] = fmaf(xr[i], wr[j], acc[i][j]);
      } else {
        float wr[4] = {wa.x, wa.y, wa.z, wa.w};
#pragma unroll
        for (int i = 0; i < 8; ++i)
#pragma unroll
          for (int j = 0; j < 4; ++j) acc[i][j] = fmaf(xr[i], wr[j], acc[i][j]);
      }
    }
    __syncthreads();
  }
#pragma unroll
  for (int i = 0; i < 8; ++i) {
    int row = row0 + r0 + i;
    if (row >= n) break;
    ushort* hrow = H + (size_t)row * COLS;
    ushort4 s0;
    s0.x = f2bf(acc[i][0]); s0.y = f2bf(acc[i][1]);
    s0.z = f2bf(acc[i][2]); s0.w = f2bf(acc[i][3]);
    *(ushort4*)&hrow[c0] = s0;
    if (COLS == 128) {
      ushort4 s1;
      s1.x = f2bf(acc[i][4]); s1.y = f2bf(acc[i][5]);
      s1.z = f2bf(acc[i][6]); s1.w = f2bf(acc[i][7]);
      *(ushort4*)&hrow[c0 + 64] = s1;
    }
  }
}

// One wave per dst node: out[d] = sum_e w_e*h[s_e] + dis[d]^2*h[d] + b  (h bf16).
template <int COLS, bool OUT_BF16>
__global__ __launch_bounds__(256) void agg_kernel(const int* __restrict__ row_start,
                                                  const uint32* __restrict__ csr,
                                                  const float* __restrict__ dis,
                                                  const ushort* __restrict__ h,
                                                  const float* __restrict__ bias,
                                                  void* __restrict__ outv, int n) {
  const int lane = threadIdx.x & 63;
  int wv = blockIdx.x * 4 + (threadIdx.x >> 6);
  const int nwv = gridDim.x * 4;
  for (int d = wv; d < n; d += nwv) {
    const int e0 = row_start[d], e1 = row_start[d + 1];
    const float dd = dis[d];
    if (COLS == 128) {
      uint32 hv = ((const uint32*)(h + (size_t)d * 128))[lane];
      float sq = dd * dd;
      float acx = sq * bf_lo(hv), acy = sq * bf_hi(hv);
      int e = e0;
      for (; e + 7 < e1; e += 8) {
        uint32 s[8], wb[8], a[8];
#pragma unroll
        for (int j = 0; j < 8; ++j) { s[j] = csr[2 * (e + j)]; wb[j] = csr[2 * (e + j) + 1]; }
#pragma unroll
        for (int j = 0; j < 8; ++j) a[j] = ((const uint32*)(h + (size_t)s[j] * 128))[lane];
#pragma unroll
        for (int j = 0; j < 8; ++j) {
          float w = __uint_as_float(wb[j]);
          acx = fmaf(w, bf_lo(a[j]), acx); acy = fmaf(w, bf_hi(a[j]), acy);
        }
      }
      for (; e + 3 < e1; e += 4) {
        uint32 s[4], wb[4], a[4];
#pragma unroll
        for (int j = 0; j < 4; ++j) { s[j] = csr[2 * (e + j)]; wb[j] = csr[2 * (e + j) + 1]; }
#pragma unroll
        for (int j = 0; j < 4; ++j) a[j] = ((const uint32*)(h + (size_t)s[j] * 128))[lane];
#pragma unroll
        for (int j = 0; j < 4; ++j) {
          float w = __uint_as_float(wb[j]);
          acx = fmaf(w, bf_lo(a[j]), acx); acy = fmaf(w, bf_hi(a[j]), acy);
        }
      }
      for (; e < e1; ++e) {
        uint32 s0 = csr[2 * e];
        float w0 = __uint_as_float(csr[2 * e + 1]);
        uint32 a0 = ((const uint32*)(h + (size_t)s0 * 128))[lane];
        acx = fmaf(w0, bf_lo(a0), acx); acy = fmaf(w0, bf_hi(a0), acy);
      }
      float2 bv = ((const float2*)bias)[lane];
      acx += bv.x; acy += bv.y;
      if (OUT_BF16) {
        uint32 pk = ((uint32)f2bf(acy) << 16) | (uint32)f2bf(acx);
        __builtin_nontemporal_store(pk, &((uint32*)outv)[(size_t)d * 64 + lane]);
      } else {
        float* o = (float*)outv + (size_t)d * 128 + 2 * lane;
        __builtin_nontemporal_store(acx, o);
        __builtin_nontemporal_store(acy, o + 1);
      }
    } else {
      float acc = dd * dd * bfu(h[(size_t)d * 64 + lane]);
      int e = e0;
      for (; e + 7 < e1; e += 8) {
        uint32 s[8], wb[8];
        float a[8];
#pragma unroll
        for (int j = 0; j < 8; ++j) { s[j] = csr[2 * (e + j)]; wb[j] = csr[2 * (e + j) + 1]; }
#pragma unroll
        for (int j = 0; j < 8; ++j) a[j] = bfu(h[(size_t)s[j] * 64 + lane]);
#pragma unroll
        for (int j = 0; j < 8; ++j) acc = fmaf(__uint_as_float(wb[j]), a[j], acc);
      }
      for (; e < e1; ++e)
        acc = fmaf(__uint_as_float(csr[2 * e + 1]), bfu(h[(size_t)csr[2 * e] * 64 + lane]), acc);
      float o = acc + bias[lane];
      __builtin_nontemporal_store(o, (float*)outv + (size_t)d * 64 + lane);
    }
  }
}

extern "C" void kernel_launch(void* const* d_in, const int* in_sizes, int n_in,
                              void* d_out, int out_size, void* d_ws, size_t ws_size,
                              hipStream_t stream) {
  const float* x  = (const float*)d_in[0];
  const int* ei   = (const int*)d_in[1];   // [2, E] int32
  const float* W1 = (const float*)d_in[2];
  const float* b1 = (const float*)d_in[3];
  const float* W2 = (const float*)d_in[4];
  const float* b2 = (const float*)d_in[5];
  float* out = (float*)d_out;

  const int N = in_sizes[0] / 128;  // 100000
  const int E = in_sizes[1] / 2;    // 1600000
  const int* srcI = ei;
  const int* dstI = ei + E;
  const int nPer = (N + 7) / 8;

  char* w = (char*)d_ws;
  float* dis      = (float*)w;                 w += (size_t)NPAD * 4;
  int* degi       = (int*)w;                   w += (size_t)NPAD * 4;
  int* row_start  = (int*)w;                   w += (size_t)NPAD * 4;
  int* cursor     = (int*)w;                   w += (size_t)NPAD * 4;
  int* bsum       = (int*)w;                   w += 4096 * 4;
  int* bcnt       = (int*)w;                   w += 64 * 4;
  int* bmeta      = (int*)w;                   w += 64 * 4;
  uint2* bucket   = (uint2*)w;                 w += (size_t)E * 8;
  uint2* csr_pack = (uint2*)w;                 w += (size_t)E * 8;
  ushort* h       = (ushort*)w;                w += (size_t)N * 128 * 2;  // bf16
  ushort* out1    = (ushort*)w;                w += (size_t)N * 128 * 2;  // bf16
  ushort* g       = h;  // layer-2 bf16 out aliases dead h

  const int nb = (N + 255) / 256;  // 391 <= 512

  // CSR build: count -> scan -> partition -> per-XCD deg -> scan -> per-XCD fill
  hipMemsetAsync(degi, 0, (size_t)N * sizeof(int), stream);
  hipMemsetAsync(bcnt, 0, 8 * sizeof(int), stream);
  count_buckets_kernel<<<512, 256, 0, stream>>>(dstI, bcnt, E, nPer);
  bucket_scan_kernel<<<1, 64, 0, stream>>>(bcnt, bmeta);
  partition_kernel<<<1024, 256, 0, stream>>>(srcI, dstI, bmeta, bucket, E, nPer);
  deg2_kernel<<<2048, 256, 0, stream>>>(bucket, bmeta, degi);
  dis_kernel<<<(N + 255) / 256, 256, 0, stream>>>(degi, dis, N);
  block_sum_kernel<<<nb, 256, 0, stream>>>(degi, bsum, N);
  scan_bsum_kernel<<<1, 512, 0, stream>>>(bsum, nb);
  scan_local_kernel<<<nb, 256, 0, stream>>>(degi, bsum, row_start, cursor, N);
  fill2_kernel<<<2048, 256, 0, stream>>>(bucket, bmeta, dis, cursor, csr_pack);

  // layer 1
  gemm_kernel<128, false, false><<<(N + 127) / 128, 256, 0, stream>>>(x, W1, h, N);
  agg_kernel<128, true><<<2048, 256, 0, stream>>>(row_start, (const uint32*)csr_pack, dis, h, b1, out1, N);

  // layer 2 (relu fused into GEMM2 load, bf16 in)
  gemm_kernel<64, true, true><<<(N + 127) / 128, 256, 0, stream>>>(out1, W2, g, N);
  agg_kernel<64, false><<<2048, 256, 0, stream>>>(row_start, (const uint32*)csr_pack, dis, g, b2, out, N);
}

// Round 8
// 541.173 us; speedup vs baseline: 1.0001x; 1.0001x over previous
//
#include <hip/hip_runtime.h>

// GCN 2-layer inference: CSR gather w/ bf16 payload, packed (src,w) CSR entries.
// CSR build: ballot-ranked dst-range partition (no LDS-atomic serialization),
// then per-XCD deg/fill passes whose working sets fit the local 4MB L2.
static constexpr int NPAD = 131072;
typedef unsigned int uint32;
typedef unsigned long long u64;

__device__ __forceinline__ ushort f2bf(float f) {  // RNE f32->bf16
  uint32 u = __float_as_uint(f);
  return (ushort)((u + 0x7FFF + ((u >> 16) & 1)) >> 16);
}
__device__ __forceinline__ float bf_lo(uint32 u) { return __uint_as_float(u << 16); }
__device__ __forceinline__ float bf_hi(uint32 u) { return __uint_as_float(u & 0xFFFF0000u); }
__device__ __forceinline__ float bfu(ushort u) { return __uint_as_float((uint32)u << 16); }

__global__ __launch_bounds__(256) void zero_kernel(int* __restrict__ degi, int n,
                                                   int* __restrict__ bcnt) {
  int i = blockIdx.x * 256 + threadIdx.x;
  if (i < n) degi[i] = 0;
  if (i < 8) bcnt[i] = 0;
}

// Ballot-based bucket histogram: no per-edge LDS atomics.
__global__ __launch_bounds__(256) void count_buckets_kernel(const int* __restrict__ dst,
                                                            int* __restrict__ bcnt,
                                                            int nE, int nPer) {
  __shared__ int c[8];
  if (threadIdx.x < 8) c[threadIdx.x] = 0;
  __syncthreads();
  const int lane = threadIdx.x & 63;
  int myCnt = 0;  // lane b (b<8) accumulates bucket b's count for this wave
  for (int i = blockIdx.x * 256 + threadIdx.x; i < nE; i += gridDim.x * 256) {
    int g = min(dst[i] / nPer, 7);
#pragma unroll
    for (int b = 0; b < 8; ++b) {
      u64 bal = __ballot(g == b);
      if (lane == b) myCnt += __popcll(bal);
    }
  }
  if (lane < 8) atomicAdd(&c[lane], myCnt);
  __syncthreads();
  if (threadIdx.x < 8 && c[threadIdx.x]) atomicAdd(&bcnt[threadIdx.x], c[threadIdx.x]);
}

__global__ __launch_bounds__(64) void bucket_scan_kernel(const int* __restrict__ bcnt,
                                                         int* __restrict__ bmeta) {
  if (threadIdx.x == 0) {
    int acc = 0;
    for (int g = 0; g < 8; ++g) {
      bmeta[g] = acc;
      bmeta[9 + g] = acc;
      acc += bcnt[g];
    }
    bmeta[8] = acc;  // = E
  }
}

// Partition edges into dst-range buckets. Rank via wave ballots (no LDS-atomic
// serialization); 8 global cursor atomics per 256-edge chunk.
__global__ __launch_bounds__(256) void partition_kernel(const int* __restrict__ src,
                                                        const int* __restrict__ dst,
                                                        int* __restrict__ bmeta,
                                                        uint2* __restrict__ bucket,
                                                        int nE, int nPer) {
  __shared__ int wcnt[4][8];
  __shared__ int wbase[4][8];
  const int lane = threadIdx.x & 63;
  const int wv = threadIdx.x >> 6;
  const u64 ltMask = (lane == 63) ? ~0ull >> 1 : (1ull << lane) - 1;
  const int nChunk = (nE + 255) / 256;
  for (int chunk = blockIdx.x; chunk < nChunk; chunk += gridDim.x) {
    int i = chunk * 256 + threadIdx.x;
    bool act = (i < nE);
    int s = 0, d = 0, g = 8;
    if (act) { d = dst[i]; s = src[i]; g = min(d / nPer, 7); }
    int rank = 0, myCnt = 0;
#pragma unroll
    for (int b = 0; b < 8; ++b) {
      u64 bal = __ballot(g == b);
      if (g == b) rank = __popcll(bal & ltMask);
      if (lane == b) myCnt = __popcll(bal);
    }
    if (lane < 8) wcnt[wv][lane] = myCnt;
    __syncthreads();
    if (threadIdx.x < 8) {
      int b = threadIdx.x;
      int tot = wcnt[0][b] + wcnt[1][b] + wcnt[2][b] + wcnt[3][b];
      int base = tot ? atomicAdd(&bmeta[9 + b], tot) : 0;
#pragma unroll
      for (int w2 = 0; w2 < 4; ++w2) { wbase[w2][b] = base; base += wcnt[w2][b]; }
    }
    __syncthreads();
    if (act) bucket[wbase[wv][g] + rank] = make_uint2((uint32)s, (uint32)d);
    __syncthreads();
  }
}

// Per-XCD degree histogram over the local bucket (degi slice is L2-resident).
__global__ __launch_bounds__(256) void deg2_kernel(const uint2* __restrict__ bucket,
                                                   const int* __restrict__ bmeta,
                                                   int* __restrict__ degi) {
  const int xcd = blockIdx.x & 7;
  const int sub = blockIdx.x >> 3;
  const int nsub = gridDim.x >> 3;
  const int b0 = bmeta[xcd], b1 = bmeta[xcd + 1];
  for (int i = b0 + sub * 256 + threadIdx.x; i < b1; i += nsub * 256)
    atomicAdd(&degi[bucket[i].y], 1);
}

__global__ __launch_bounds__(256) void block_sum_kernel(const int* __restrict__ degi,
                                                        int* __restrict__ bsum, int n) {
  __shared__ int sm[256];
  int i = blockIdx.x * 256 + threadIdx.x;
  sm[threadIdx.x] = (i < n) ? degi[i] : 0;
  __syncthreads();
  for (int s = 128; s > 0; s >>= 1) {
    if (threadIdx.x < s) sm[threadIdx.x] += sm[threadIdx.x + s];
    __syncthreads();
  }
  if (threadIdx.x == 0) bsum[blockIdx.x] = sm[0];
}

__global__ __launch_bounds__(512) void scan_bsum_kernel(int* __restrict__ bsum, int nb) {
  __shared__ int sm[512];
  int v = (threadIdx.x < nb) ? bsum[threadIdx.x] : 0;
  sm[threadIdx.x] = v;
  __syncthreads();
  for (int off = 1; off < 512; off <<= 1) {
    int t = (threadIdx.x >= off) ? sm[threadIdx.x - off] : 0;
    __syncthreads();
    sm[threadIdx.x] += t;
    __syncthreads();
  }
  if (threadIdx.x < nb) bsum[threadIdx.x] = sm[threadIdx.x] - v;  // exclusive
}

// Local scan -> row_start/cursor; also computes dis[i] (fused).
__global__ __launch_bounds__(256) void scan_local_kernel(const int* __restrict__ degi,
                                                         const int* __restrict__ bsum,
                                                         int* __restrict__ row_start,
                                                         int* __restrict__ cursor,
                                                         float* __restrict__ dis, int n) {
  __shared__ int sm[256];
  int i = blockIdx.x * 256 + threadIdx.x;
  int v = (i < n) ? degi[i] : 0;
  sm[threadIdx.x] = v;
  __syncthreads();
  for (int off = 1; off < 256; off <<= 1) {
    int t = (threadIdx.x >= off) ? sm[threadIdx.x - off] : 0;
    __syncthreads();
    sm[threadIdx.x] += t;
    __syncthreads();
  }
  int excl = sm[threadIdx.x] - v + bsum[blockIdx.x];
  if (i < n) {
    row_start[i] = excl;
    cursor[i] = excl;
    dis[i] = rsqrtf((float)v + 1.0f);  // +1 = self loop
  }
  if (i == n - 1) row_start[n] = excl + v;  // = E
}

// Per-XCD CSR fill from the local bucket; dirty CSR slice (1.6MB) + cursors
// (50KB) + bucket stream (1.6MB) all fit the local L2.
__global__ __launch_bounds__(256) void fill2_kernel(const uint2* __restrict__ bucket,
                                                    const int* __restrict__ bmeta,
                                                    const float* __restrict__ dis,
                                                    int* __restrict__ cursor,
                                                    uint2* __restrict__ csr_pack) {
  const int xcd = blockIdx.x & 7;
  const int sub = blockIdx.x >> 3;
  const int nsub = gridDim.x >> 3;
  const int b0 = bmeta[xcd], b1 = bmeta[xcd + 1];
  for (int i = b0 + sub * 256 + threadIdx.x; i < b1; i += nsub * 256) {
    uint2 e = bucket[i];
    int pos = atomicAdd(&cursor[e.y], 1);
    csr_pack[pos] = make_uint2(e.x, __float_as_uint(dis[e.x] * dis[e.y]));
  }
}

// H_bf16[128rows x COLS] = (relu?)X[128rows x 128] @ W[128 x COLS]; X fp32 or bf16.
template <int COLS, bool RELU_IN, bool IN_BF16>
__global__ __launch_bounds__(256) void gemm_kernel(const void* __restrict__ Xv,
                                                   const float* __restrict__ W,
                                                   ushort* __restrict__ H, int n) {
  constexpr int KC = 32;
  constexpr int RT = 132;
  constexpr int TN = (COLS == 128) ? 8 : 4;
  __shared__ float sX[KC][RT];
  __shared__ float sW[KC][COLS];
  const int t = threadIdx.x;
  const int row0 = blockIdx.x * 128;
  const int r0 = (t >> 4) * 8;
  const int c0 = (t & 15) * 4;

  float acc[8][TN];
#pragma unroll
  for (int i = 0; i < 8; ++i)
#pragma unroll
    for (int j = 0; j < TN; ++j) acc[i][j] = 0.f;

  for (int k0 = 0; k0 < 128; k0 += KC) {
#pragma unroll
    for (int p = 0; p < 4; ++p) {
      int idx = p * 256 + t;
      int r = idx >> 3;
      int f = idx & 7;
      int gr = row0 + r;
      float4 v = make_float4(0.f, 0.f, 0.f, 0.f);
      if (gr < n) {
        if (IN_BF16) {
          const ushort* Xb = (const ushort*)Xv;
          ushort4 uv = *(const ushort4*)(Xb + (size_t)gr * 128 + k0 + f * 4);
          v = make_float4(bfu(uv.x), bfu(uv.y), bfu(uv.z), bfu(uv.w));
        } else {
          v = *(const float4*)((const float*)Xv + (size_t)gr * 128 + k0 + f * 4);
        }
      }
      if (RELU_IN) {
        v.x = fmaxf(v.x, 0.f); v.y = fmaxf(v.y, 0.f);
        v.z = fmaxf(v.z, 0.f); v.w = fmaxf(v.w, 0.f);
      }
      int kk = f * 4;
      sX[kk + 0][r] = v.x; sX[kk + 1][r] = v.y;
      sX[kk + 2][r] = v.z; sX[kk + 3][r] = v.w;
    }
    constexpr int WP = (KC * COLS) / (256 * 4);
#pragma unroll
    for (int p = 0; p < WP; ++p) {
      int idx = p * 256 + t;
      int k = idx / (COLS / 4);
      int c4 = idx % (COLS / 4);
      *(float4*)&sW[k][c4 * 4] = *(const float4*)(W + (size_t)(k0 + k) * COLS + c4 * 4);
    }
    __syncthreads();
#pragma unroll 8
    for (int k = 0; k < KC; ++k) {
      float4 xa = *(const float4*)&sX[k][r0];
      float4 xb = *(const float4*)&sX[k][r0 + 4];
      float4 wa = *(const float4*)&sW[k][c0];
      float xr[8] = {xa.x, xa.y, xa.z, xa.w, xb.x, xb.y, xb.z, xb.w};
      if (COLS == 128) {
        float4 wb = *(const float4*)&sW[k][c0 + 64];
        float wr[8] = {wa.x, wa.y, wa.z, wa.w, wb.x, wb.y, wb.z, wb.w};
#pragma unroll
        for (int i = 0; i < 8; ++i)
#pragma unroll
          for (int j = 0; j < 8; ++j) acc[i][j] = fmaf(xr[i], wr[j], acc[i][j]);
      } else {
        float wr[4] = {wa.x, wa.y, wa.z, wa.w};
#pragma unroll
        for (int i = 0; i < 8; ++i)
#pragma unroll
          for (int j = 0; j < 4; ++j) acc[i][j] = fmaf(xr[i], wr[j], acc[i][j]);
      }
    }
    __syncthreads();
  }
#pragma unroll
  for (int i = 0; i < 8; ++i) {
    int row = row0 + r0 + i;
    if (row >= n) break;
    ushort* hrow = H + (size_t)row * COLS;
    ushort4 s0;
    s0.x = f2bf(acc[i][0]); s0.y = f2bf(acc[i][1]);
    s0.z = f2bf(acc[i][2]); s0.w = f2bf(acc[i][3]);
    *(ushort4*)&hrow[c0] = s0;
    if (COLS == 128) {
      ushort4 s1;
      s1.x = f2bf(acc[i][4]); s1.y = f2bf(acc[i][5]);
      s1.z = f2bf(acc[i][6]); s1.w = f2bf(acc[i][7]);
      *(ushort4*)&hrow[c0 + 64] = s1;
    }
  }
}

// One wave per dst node: out[d] = sum_e w_e*h[s_e] + dis[d]^2*h[d] + b  (h bf16).
template <int COLS, bool OUT_BF16>
__global__ __launch_bounds__(256) void agg_kernel(const int* __restrict__ row_start,
                                                  const uint32* __restrict__ csr,
                                                  const float* __restrict__ dis,
                                                  const ushort* __restrict__ h,
                                                  const float* __restrict__ bias,
                                                  void* __restrict__ outv, int n) {
  const int lane = threadIdx.x & 63;
  int wv = blockIdx.x * 4 + (threadIdx.x >> 6);
  const int nwv = gridDim.x * 4;
  for (int d = wv; d < n; d += nwv) {
    const int e0 = row_start[d], e1 = row_start[d + 1];
    const float dd = dis[d];
    if (COLS == 128) {
      uint32 hv = ((const uint32*)(h + (size_t)d * 128))[lane];
      float sq = dd * dd;
      float acx = sq * bf_lo(hv), acy = sq * bf_hi(hv);
      int e = e0;
      for (; e + 7 < e1; e += 8) {
        uint32 s[8], wb[8], a[8];
#pragma unroll
        for (int j = 0; j < 8; ++j) { s[j] = csr[2 * (e + j)]; wb[j] = csr[2 * (e + j) + 1]; }
#pragma unroll
        for (int j = 0; j < 8; ++j) a[j] = ((const uint32*)(h + (size_t)s[j] * 128))[lane];
#pragma unroll
        for (int j = 0; j < 8; ++j) {
          float w = __uint_as_float(wb[j]);
          acx = fmaf(w, bf_lo(a[j]), acx); acy = fmaf(w, bf_hi(a[j]), acy);
        }
      }
      for (; e + 3 < e1; e += 4) {
        uint32 s[4], wb[4], a[4];
#pragma unroll
        for (int j = 0; j < 4; ++j) { s[j] = csr[2 * (e + j)]; wb[j] = csr[2 * (e + j) + 1]; }
#pragma unroll
        for (int j = 0; j < 4; ++j) a[j] = ((const uint32*)(h + (size_t)s[j] * 128))[lane];
#pragma unroll
        for (int j = 0; j < 4; ++j) {
          float w = __uint_as_float(wb[j]);
          acx = fmaf(w, bf_lo(a[j]), acx); acy = fmaf(w, bf_hi(a[j]), acy);
        }
      }
      for (; e < e1; ++e) {
        uint32 s0 = csr[2 * e];
        float w0 = __uint_as_float(csr[2 * e + 1]);
        uint32 a0 = ((const uint32*)(h + (size_t)s0 * 128))[lane];
        acx = fmaf(w0, bf_lo(a0), acx); acy = fmaf(w0, bf_hi(a0), acy);
      }
      float2 bv = ((const float2*)bias)[lane];
      acx += bv.x; acy += bv.y;
      if (OUT_BF16) {
        uint32 pk = ((uint32)f2bf(acy) << 16) | (uint32)f2bf(acx);
        __builtin_nontemporal_store(pk, &((uint32*)outv)[(size_t)d * 64 + lane]);
      } else {
        float* o = (float*)outv + (size_t)d * 128 + 2 * lane;
        __builtin_nontemporal_store(acx, o);
        __builtin_nontemporal_store(acy, o + 1);
      }
    } else {
      float acc = dd * dd * bfu(h[(size_t)d * 64 + lane]);
      int e = e0;
      for (; e + 7 < e1; e += 8) {
        uint32 s[8], wb[8];
        float a[8];
#pragma unroll
        for (int j = 0; j < 8; ++j) { s[j] = csr[2 * (e + j)]; wb[j] = csr[2 * (e + j) + 1]; }
#pragma unroll
        for (int j = 0; j < 8; ++j) a[j] = bfu(h[(size_t)s[j] * 64 + lane]);
#pragma unroll
        for (int j = 0; j < 8; ++j) acc = fmaf(__uint_as_float(wb[j]), a[j], acc);
      }
      for (; e < e1; ++e)
        acc = fmaf(__uint_as_float(csr[2 * e + 1]), bfu(h[(size_t)csr[2 * e] * 64 + lane]), acc);
      float o = acc + bias[lane];
      __builtin_nontemporal_store(o, (float*)outv + (size_t)d * 64 + lane);
    }
  }
}

extern "C" void kernel_launch(void* const* d_in, const int* in_sizes, int n_in,
                              void* d_out, int out_size, void* d_ws, size_t ws_size,
                              hipStream_t stream) {
  const float* x  = (const float*)d_in[0];
  const int* ei   = (const int*)d_in[1];   // [2, E] int32
  const float* W1 = (const float*)d_in[2];
  const float* b1 = (const float*)d_in[3];
  const float* W2 = (const float*)d_in[4];
  const float* b2 = (const float*)d_in[5];
  float* out = (float*)d_out;

  const int N = in_sizes[0] / 128;  // 100000
  const int E = in_sizes[1] / 2;    // 1600000
  const int* srcI = ei;
  const int* dstI = ei + E;
  const int nPer = (N + 7) / 8;

  char* w = (char*)d_ws;
  float* dis      = (float*)w;                 w += (size_t)NPAD * 4;
  int* degi       = (int*)w;                   w += (size_t)NPAD * 4;
  int* row_start  = (int*)w;                   w += (size_t)NPAD * 4;
  int* cursor     = (int*)w;                   w += (size_t)NPAD * 4;
  int* bsum       = (int*)w;                   w += 4096 * 4;
  int* bcnt       = (int*)w;                   w += 64 * 4;
  int* bmeta      = (int*)w;                   w += 64 * 4;
  uint2* bucket   = (uint2*)w;                 w += (size_t)E * 8;
  uint2* csr_pack = (uint2*)w;                 w += (size_t)E * 8;
  ushort* h       = (ushort*)w;                w += (size_t)N * 128 * 2;  // bf16
  ushort* out1    = (ushort*)w;                w += (size_t)N * 128 * 2;  // bf16
  ushort* g       = h;  // layer-2 bf16 out aliases dead h

  const int nb = (N + 255) / 256;  // 391 <= 512

  // CSR build: zero -> count -> scan -> partition -> per-XCD deg ->
  //            blockscan chain (+dis fused) -> per-XCD fill
  zero_kernel<<<nb, 256, 0, stream>>>(degi, N, bcnt);
  count_buckets_kernel<<<256, 256, 0, stream>>>(dstI, bcnt, E, nPer);
  bucket_scan_kernel<<<1, 64, 0, stream>>>(bcnt, bmeta);
  partition_kernel<<<1024, 256, 0, stream>>>(srcI, dstI, bmeta, bucket, E, nPer);
  deg2_kernel<<<2048, 256, 0, stream>>>(bucket, bmeta, degi);
  block_sum_kernel<<<nb, 256, 0, stream>>>(degi, bsum, N);
  scan_bsum_kernel<<<1, 512, 0, stream>>>(bsum, nb);
  scan_local_kernel<<<nb, 256, 0, stream>>>(degi, bsum, row_start, cursor, dis, N);
  fill2_kernel<<<2048, 256, 0, stream>>>(bucket, bmeta, dis, cursor, csr_pack);

  // layer 1
  gemm_kernel<128, false, false><<<(N + 127) / 128, 256, 0, stream>>>(x, W1, h, N);
  agg_kernel<128, true><<<2048, 256, 0, stream>>>(row_start, (const uint32*)csr_pack, dis, h, b1, out1, N);

  // layer 2 (relu fused into GEMM2 load, bf16 in)
  gemm_kernel<64, true, true><<<(N + 127) / 128, 256, 0, stream>>>(out1, W2, g, N);
  agg_kernel<64, false><<<2048, 256, 0, stream>>>(row_start, (const uint32*)csr_pack, dis, g, b2, out, N);
}

// Round 9
// 511.767 us; speedup vs baseline: 1.0576x; 1.0575x over previous
//
#include <hip/hip_runtime.h>

// GCN 2-layer inference: CSR gather w/ bf16 payload, packed (src,w) CSR entries.
// CSR build: atomic-free deterministic 3-phase dst-range partition
// (per-wave ballot counts -> shfl-scan bases -> rank-write), then per-XCD
// deg/fill passes whose working sets fit the local 4MB L2.
static constexpr int NPAD = 131072;
static constexpr int NWAVE = 4096;  // partition waves (fixed)
typedef unsigned int uint32;
typedef unsigned long long u64;

__device__ __forceinline__ ushort f2bf(float f) {  // RNE f32->bf16
  uint32 u = __float_as_uint(f);
  return (ushort)((u + 0x7FFF + ((u >> 16) & 1)) >> 16);
}
__device__ __forceinline__ float bf_lo(uint32 u) { return __uint_as_float(u << 16); }
__device__ __forceinline__ float bf_hi(uint32 u) { return __uint_as_float(u & 0xFFFF0000u); }
__device__ __forceinline__ float bfu(ushort u) { return __uint_as_float((uint32)u << 16); }

__global__ __launch_bounds__(256) void zero_kernel(int* __restrict__ degi, int n) {
  int i = blockIdx.x * 256 + threadIdx.x;
  if (i < n) degi[i] = 0;
}

// Phase A: per-wave per-bucket counts over the wave's fixed edge range.
__global__ __launch_bounds__(256) void count_kernel(const int* __restrict__ dst,
                                                    int* __restrict__ wcnt,
                                                    int nE, int nPer, int span) {
  const int W = blockIdx.x * 4 + (threadIdx.x >> 6);
  const int lane = threadIdx.x & 63;
  const int s0 = W * span;
  const int s1 = min(s0 + span, nE);
  int cnt = 0;  // lane b accumulates bucket b
  for (int base = s0; base < s1; base += 64) {
    int i = base + lane;
    int g = 8;
    if (i < s1) g = min(dst[i] / nPer, 7);
#pragma unroll
    for (int b = 0; b < 8; ++b) {
      u64 bal = __ballot(g == b);
      if (lane == b) cnt += __popcll(bal);
    }
  }
  if (lane < 8) wcnt[W * 8 + lane] = cnt;
}

// Phase B: one block; wave b shfl-scans bucket b's 4096 counts -> exclusive
// bases (wbase) + bucket bases (bmeta[0..8]).
__global__ __launch_bounds__(512) void wave_scan_kernel(const int* __restrict__ wcnt,
                                                        int* __restrict__ wbase,
                                                        int* __restrict__ bmeta) {
  __shared__ int tot[8];
  __shared__ int bbase[9];
  const int b = threadIdx.x >> 6;    // bucket
  const int lane = threadIdx.x & 63; // handles waves [lane*64, lane*64+64)
  const int w0 = lane * 64;
  int lsum = 0;
  for (int k = 0; k < 64; ++k) lsum += wcnt[(w0 + k) * 8 + b];
  int incl = lsum;
  for (int off = 1; off < 64; off <<= 1) {
    int t = __shfl_up(incl, off);
    if (lane >= off) incl += t;
  }
  int excl = incl - lsum;
  if (lane == 63) tot[b] = incl;
  __syncthreads();
  if (threadIdx.x == 0) {
    int acc = 0;
    for (int j = 0; j < 8; ++j) { bbase[j] = acc; acc += tot[j]; }
    bbase[8] = acc;  // = E
  }
  __syncthreads();
  int running = bbase[b] + excl;
  for (int k = 0; k < 64; ++k) {
    int idx = (w0 + k) * 8 + b;
    int c = wcnt[idx];
    wbase[idx] = running;
    running += c;
  }
  if (threadIdx.x < 9) bmeta[threadIdx.x] = bbase[threadIdx.x];
}

// Phase C: partition. No atomics, no LDS, no barriers: lane b's register is
// bucket b's running base; ranks from ballots; bases broadcast via shfl.
__global__ __launch_bounds__(256) void partition_kernel(const int* __restrict__ src,
                                                        const int* __restrict__ dst,
                                                        const int* __restrict__ wbase,
                                                        uint2* __restrict__ bucket,
                                                        int nE, int nPer, int span) {
  const int W = blockIdx.x * 4 + (threadIdx.x >> 6);
  const int lane = threadIdx.x & 63;
  const u64 ltMask = (lane == 63) ? ~0ull >> 1 : (1ull << lane) - 1;
  const int s0 = W * span;
  const int s1 = min(s0 + span, nE);
  int base_reg = (lane < 8) ? wbase[W * 8 + lane] : 0;
  for (int c0 = s0; c0 < s1; c0 += 64) {
    int i = c0 + lane;
    bool act = (i < s1);
    int s = 0, d = 0, g = 8;
    if (act) { d = dst[i]; s = src[i]; g = min(d / nPer, 7); }
    int rank = 0, mycnt = 0;
#pragma unroll
    for (int b = 0; b < 8; ++b) {
      u64 bal = __ballot(g == b);
      if (g == b) rank = __popcll(bal & ltMask);
      if (lane == b) mycnt = __popcll(bal);
    }
    int dest = __shfl(base_reg, g) + rank;  // g==8 -> garbage, store guarded
    if (act) bucket[dest] = make_uint2((uint32)s, (uint32)d);
    if (lane < 8) base_reg += mycnt;
  }
}

// Per-XCD degree histogram over the local bucket (degi slice is L2-resident).
__global__ __launch_bounds__(256) void deg2_kernel(const uint2* __restrict__ bucket,
                                                   const int* __restrict__ bmeta,
                                                   int* __restrict__ degi) {
  const int xcd = blockIdx.x & 7;
  const int sub = blockIdx.x >> 3;
  const int nsub = gridDim.x >> 3;
  const int b0 = bmeta[xcd], b1 = bmeta[xcd + 1];
  for (int i = b0 + sub * 256 + threadIdx.x; i < b1; i += nsub * 256)
    atomicAdd(&degi[bucket[i].y], 1);
}

__global__ __launch_bounds__(256) void block_sum_kernel(const int* __restrict__ degi,
                                                        int* __restrict__ bsum, int n) {
  __shared__ int sm[256];
  int i = blockIdx.x * 256 + threadIdx.x;
  sm[threadIdx.x] = (i < n) ? degi[i] : 0;
  __syncthreads();
  for (int s = 128; s > 0; s >>= 1) {
    if (threadIdx.x < s) sm[threadIdx.x] += sm[threadIdx.x + s];
    __syncthreads();
  }
  if (threadIdx.x == 0) bsum[blockIdx.x] = sm[0];
}

__global__ __launch_bounds__(512) void scan_bsum_kernel(int* __restrict__ bsum, int nb) {
  __shared__ int sm[512];
  int v = (threadIdx.x < nb) ? bsum[threadIdx.x] : 0;
  sm[threadIdx.x] = v;
  __syncthreads();
  for (int off = 1; off < 512; off <<= 1) {
    int t = (threadIdx.x >= off) ? sm[threadIdx.x - off] : 0;
    __syncthreads();
    sm[threadIdx.x] += t;
    __syncthreads();
  }
  if (threadIdx.x < nb) bsum[threadIdx.x] = sm[threadIdx.x] - v;  // exclusive
}

// Local scan -> row_start/cursor; also computes dis[i] (fused).
__global__ __launch_bounds__(256) void scan_local_kernel(const int* __restrict__ degi,
                                                         const int* __restrict__ bsum,
                                                         int* __restrict__ row_start,
                                                         int* __restrict__ cursor,
                                                         float* __restrict__ dis, int n) {
  __shared__ int sm[256];
  int i = blockIdx.x * 256 + threadIdx.x;
  int v = (i < n) ? degi[i] : 0;
  sm[threadIdx.x] = v;
  __syncthreads();
  for (int off = 1; off < 256; off <<= 1) {
    int t = (threadIdx.x >= off) ? sm[threadIdx.x - off] : 0;
    __syncthreads();
    sm[threadIdx.x] += t;
    __syncthreads();
  }
  int excl = sm[threadIdx.x] - v + bsum[blockIdx.x];
  if (i < n) {
    row_start[i] = excl;
    cursor[i] = excl;
    dis[i] = rsqrtf((float)v + 1.0f);  // +1 = self loop
  }
  if (i == n - 1) row_start[n] = excl + v;  // = E
}

// Per-XCD CSR fill from the local bucket; dirty CSR slice (1.6MB) + cursors
// (50KB) + bucket stream (1.6MB) all fit the local L2.
__global__ __launch_bounds__(256) void fill2_kernel(const uint2* __restrict__ bucket,
                                                    const int* __restrict__ bmeta,
                                                    const float* __restrict__ dis,
                                                    int* __restrict__ cursor,
                                                    uint2* __restrict__ csr_pack) {
  const int xcd = blockIdx.x & 7;
  const int sub = blockIdx.x >> 3;
  const int nsub = gridDim.x >> 3;
  const int b0 = bmeta[xcd], b1 = bmeta[xcd + 1];
  for (int i = b0 + sub * 256 + threadIdx.x; i < b1; i += nsub * 256) {
    uint2 e = bucket[i];
    int pos = atomicAdd(&cursor[e.y], 1);
    csr_pack[pos] = make_uint2(e.x, __float_as_uint(dis[e.x] * dis[e.y]));
  }
}

// H_bf16[128rows x COLS] = (relu?)X[128rows x 128] @ W[128 x COLS]; X fp32 or bf16.
template <int COLS, bool RELU_IN, bool IN_BF16>
__global__ __launch_bounds__(256) void gemm_kernel(const void* __restrict__ Xv,
                                                   const float* __restrict__ W,
                                                   ushort* __restrict__ H, int n) {
  constexpr int KC = 32;
  constexpr int RT = 132;
  constexpr int TN = (COLS == 128) ? 8 : 4;
  __shared__ float sX[KC][RT];
  __shared__ float sW[KC][COLS];
  const int t = threadIdx.x;
  const int row0 = blockIdx.x * 128;
  const int r0 = (t >> 4) * 8;
  const int c0 = (t & 15) * 4;

  float acc[8][TN];
#pragma unroll
  for (int i = 0; i < 8; ++i)
#pragma unroll
    for (int j = 0; j < TN; ++j) acc[i][j] = 0.f;

  for (int k0 = 0; k0 < 128; k0 += KC) {
#pragma unroll
    for (int p = 0; p < 4; ++p) {
      int idx = p * 256 + t;
      int r = idx >> 3;
      int f = idx & 7;
      int gr = row0 + r;
      float4 v = make_float4(0.f, 0.f, 0.f, 0.f);
      if (gr < n) {
        if (IN_BF16) {
          const ushort* Xb = (const ushort*)Xv;
          ushort4 uv = *(const ushort4*)(Xb + (size_t)gr * 128 + k0 + f * 4);
          v = make_float4(bfu(uv.x), bfu(uv.y), bfu(uv.z), bfu(uv.w));
        } else {
          v = *(const float4*)((const float*)Xv + (size_t)gr * 128 + k0 + f * 4);
        }
      }
      if (RELU_IN) {
        v.x = fmaxf(v.x, 0.f); v.y = fmaxf(v.y, 0.f);
        v.z = fmaxf(v.z, 0.f); v.w = fmaxf(v.w, 0.f);
      }
      int kk = f * 4;
      sX[kk + 0][r] = v.x; sX[kk + 1][r] = v.y;
      sX[kk + 2][r] = v.z; sX[kk + 3][r] = v.w;
    }
    constexpr int WP = (KC * COLS) / (256 * 4);
#pragma unroll
    for (int p = 0; p < WP; ++p) {
      int idx = p * 256 + t;
      int k = idx / (COLS / 4);
      int c4 = idx % (COLS / 4);
      *(float4*)&sW[k][c4 * 4] = *(const float4*)(W + (size_t)(k0 + k) * COLS + c4 * 4);
    }
    __syncthreads();
#pragma unroll 8
    for (int k = 0; k < KC; ++k) {
      float4 xa = *(const float4*)&sX[k][r0];
      float4 xb = *(const float4*)&sX[k][r0 + 4];
      float4 wa = *(const float4*)&sW[k][c0];
      float xr[8] = {xa.x, xa.y, xa.z, xa.w, xb.x, xb.y, xb.z, xb.w};
      if (COLS == 128) {
        float4 wb = *(const float4*)&sW[k][c0 + 64];
        float wr[8] = {wa.x, wa.y, wa.z, wa.w, wb.x, wb.y, wb.z, wb.w};
#pragma unroll
        for (int i = 0; i < 8; ++i)
#pragma unroll
          for (int j = 0; j < 8; ++j) acc[i][j] = fmaf(xr[i], wr[j], acc[i][j]);
      } else {
        float wr[4] = {wa.x, wa.y, wa.z, wa.w};
#pragma unroll
        for (int i = 0; i < 8; ++i)
#pragma unroll
          for (int j = 0; j < 4; ++j) acc[i][j] = fmaf(xr[i], wr[j], acc[i][j]);
      }
    }
    __syncthreads();
  }
#pragma unroll
  for (int i = 0; i < 8; ++i) {
    int row = row0 + r0 + i;
    if (row >= n) break;
    ushort* hrow = H + (size_t)row * COLS;
    ushort4 s0;
    s0.x = f2bf(acc[i][0]); s0.y = f2bf(acc[i][1]);
    s0.z = f2bf(acc[i][2]); s0.w = f2bf(acc[i][3]);
    *(ushort4*)&hrow[c0] = s0;
    if (COLS == 128) {
      ushort4 s1;
      s1.x = f2bf(acc[i][4]); s1.y = f2bf(acc[i][5]);
      s1.z = f2bf(acc[i][6]); s1.w = f2bf(acc[i][7]);
      *(ushort4*)&hrow[c0 + 64] = s1;
    }
  }
}

// One wave per dst node: out[d] = sum_e w_e*h[s_e] + dis[d]^2*h[d] + b  (h bf16).
template <int COLS, bool OUT_BF16>
__global__ __launch_bounds__(256) void agg_kernel(const int* __restrict__ row_start,
                                                  const uint32* __restrict__ csr,
                                                  const float* __restrict__ dis,
                                                  const ushort* __restrict__ h,
                                                  const float* __restrict__ bias,
                                                  void* __restrict__ outv, int n) {
  const int lane = threadIdx.x & 63;
  int wv = blockIdx.x * 4 + (threadIdx.x >> 6);
  const int nwv = gridDim.x * 4;
  for (int d = wv; d < n; d += nwv) {
    const int e0 = row_start[d], e1 = row_start[d + 1];
    const float dd = dis[d];
    if (COLS == 128) {
      uint32 hv = ((const uint32*)(h + (size_t)d * 128))[lane];
      float sq = dd * dd;
      float acx = sq * bf_lo(hv), acy = sq * bf_hi(hv);
      int e = e0;
      for (; e + 7 < e1; e += 8) {
        uint32 s[8], wb[8], a[8];
#pragma unroll
        for (int j = 0; j < 8; ++j) { s[j] = csr[2 * (e + j)]; wb[j] = csr[2 * (e + j) + 1]; }
#pragma unroll
        for (int j = 0; j < 8; ++j) a[j] = ((const uint32*)(h + (size_t)s[j] * 128))[lane];
#pragma unroll
        for (int j = 0; j < 8; ++j) {
          float w = __uint_as_float(wb[j]);
          acx = fmaf(w, bf_lo(a[j]), acx); acy = fmaf(w, bf_hi(a[j]), acy);
        }
      }
      for (; e + 3 < e1; e += 4) {
        uint32 s[4], wb[4], a[4];
#pragma unroll
        for (int j = 0; j < 4; ++j) { s[j] = csr[2 * (e + j)]; wb[j] = csr[2 * (e + j) + 1]; }
#pragma unroll
        for (int j = 0; j < 4; ++j) a[j] = ((const uint32*)(h + (size_t)s[j] * 128))[lane];
#pragma unroll
        for (int j = 0; j < 4; ++j) {
          float w = __uint_as_float(wb[j]);
          acx = fmaf(w, bf_lo(a[j]), acx); acy = fmaf(w, bf_hi(a[j]), acy);
        }
      }
      for (; e < e1; ++e) {
        uint32 s0 = csr[2 * e];
        float w0 = __uint_as_float(csr[2 * e + 1]);
        uint32 a0 = ((const uint32*)(h + (size_t)s0 * 128))[lane];
        acx = fmaf(w0, bf_lo(a0), acx); acy = fmaf(w0, bf_hi(a0), acy);
      }
      float2 bv = ((const float2*)bias)[lane];
      acx += bv.x; acy += bv.y;
      if (OUT_BF16) {
        uint32 pk = ((uint32)f2bf(acy) << 16) | (uint32)f2bf(acx);
        __builtin_nontemporal_store(pk, &((uint32*)outv)[(size_t)d * 64 + lane]);
      } else {
        float* o = (float*)outv + (size_t)d * 128 + 2 * lane;
        __builtin_nontemporal_store(acx, o);
        __builtin_nontemporal_store(acy, o + 1);
      }
    } else {
      float acc = dd * dd * bfu(h[(size_t)d * 64 + lane]);
      int e = e0;
      for (; e + 7 < e1; e += 8) {
        uint32 s[8], wb[8];
        float a[8];
#pragma unroll
        for (int j = 0; j < 8; ++j) { s[j] = csr[2 * (e + j)]; wb[j] = csr[2 * (e + j) + 1]; }
#pragma unroll
        for (int j = 0; j < 8; ++j) a[j] = bfu(h[(size_t)s[j] * 64 + lane]);
#pragma unroll
        for (int j = 0; j < 8; ++j) acc = fmaf(__uint_as_float(wb[j]), a[j], acc);
      }
      for (; e < e1; ++e)
        acc = fmaf(__uint_as_float(csr[2 * e + 1]), bfu(h[(size_t)csr[2 * e] * 64 + lane]), acc);
      float o = acc + bias[lane];
      __builtin_nontemporal_store(o, (float*)outv + (size_t)d * 64 + lane);
    }
  }
}

extern "C" void kernel_launch(void* const* d_in, const int* in_sizes, int n_in,
                              void* d_out, int out_size, void* d_ws, size_t ws_size,
                              hipStream_t stream) {
  const float* x  = (const float*)d_in[0];
  const int* ei   = (const int*)d_in[1];   // [2, E] int32
  const float* W1 = (const float*)d_in[2];
  const float* b1 = (const float*)d_in[3];
  const float* W2 = (const float*)d_in[4];
  const float* b2 = (const float*)d_in[5];
  float* out = (float*)d_out;

  const int N = in_sizes[0] / 128;  // 100000
  const int E = in_sizes[1] / 2;    // 1600000
  const int* srcI = ei;
  const int* dstI = ei + E;
  const int nPer = (N + 7) / 8;
  const int span = (E + NWAVE - 1) / NWAVE;

  char* w = (char*)d_ws;
  float* dis      = (float*)w;                 w += (size_t)NPAD * 4;
  int* degi       = (int*)w;                   w += (size_t)NPAD * 4;
  int* row_start  = (int*)w;                   w += (size_t)NPAD * 4;
  int* cursor     = (int*)w;                   w += (size_t)NPAD * 4;
  int* bsum       = (int*)w;                   w += 4096 * 4;
  int* bmeta      = (int*)w;                   w += 64 * 4;
  int* wcnt       = (int*)w;                   w += (size_t)NWAVE * 8 * 4;
  int* wbase      = (int*)w;                   w += (size_t)NWAVE * 8 * 4;
  uint2* bucket   = (uint2*)w;                 w += (size_t)E * 8;
  uint2* csr_pack = (uint2*)w;                 w += (size_t)E * 8;
  ushort* h       = (ushort*)w;                w += (size_t)N * 128 * 2;  // bf16
  ushort* out1    = (ushort*)w;                w += (size_t)N * 128 * 2;  // bf16
  ushort* g       = h;  // layer-2 bf16 out aliases dead h

  const int nb = (N + 255) / 256;  // 391 <= 512

  // CSR build: zero -> count -> wave_scan -> partition (all atomic-free) ->
  //            per-XCD deg -> blockscan chain (+dis fused) -> per-XCD fill
  zero_kernel<<<nb, 256, 0, stream>>>(degi, N);
  count_kernel<<<NWAVE / 4, 256, 0, stream>>>(dstI, wcnt, E, nPer, span);
  wave_scan_kernel<<<1, 512, 0, stream>>>(wcnt, wbase, bmeta);
  partition_kernel<<<NWAVE / 4, 256, 0, stream>>>(srcI, dstI, wbase, bucket, E, nPer, span);
  deg2_kernel<<<2048, 256, 0, stream>>>(bucket, bmeta, degi);
  block_sum_kernel<<<nb, 256, 0, stream>>>(degi, bsum, N);
  scan_bsum_kernel<<<1, 512, 0, stream>>>(bsum, nb);
  scan_local_kernel<<<nb, 256, 0, stream>>>(degi, bsum, row_start, cursor, dis, N);
  fill2_kernel<<<2048, 256, 0, stream>>>(bucket, bmeta, dis, cursor, csr_pack);

  // layer 1
  gemm_kernel<128, false, false><<<(N + 127) / 128, 256, 0, stream>>>(x, W1, h, N);
  agg_kernel<128, true><<<2048, 256, 0, stream>>>(row_start, (const uint32*)csr_pack, dis, h, b1, out1, N);

  // layer 2 (relu fused into GEMM2 load, bf16 in)
  gemm_kernel<64, true, true><<<(N + 127) / 128, 256, 0, stream>>>(out1, W2, g, N);
  agg_kernel<64, false><<<2048, 256, 0, stream>>>(row_start, (const uint32*)csr_pack, dis, g, b2, out, N);
}